// Round 11
// baseline (175.695 us; speedup 1.0000x reference)
//
#include <hip/hip_runtime.h>
#include <hip/hip_bf16.h>
#include <math.h>

constexpr int NB  = 16;
constexpr int NT  = 1024;
constexpr int ND  = 128;
constexpr int NH  = 8;
constexpr int NHS = 16;
constexpr int NDH = 512;
constexpr long NBT = (long)NB * NT;   // 16384 tokens

typedef __attribute__((ext_vector_type(8))) short short8;
typedef __attribute__((ext_vector_type(4))) float f32x4;
typedef __attribute__((ext_vector_type(4))) unsigned short us4;

__device__ __forceinline__ unsigned short f2bf(float f) {
    __hip_bfloat16 h = __float2bfloat16(f);
    return *(unsigned short*)&h;
}

// f32[8] -> bf16x8 fragment (RNE packed converts)
__device__ __forceinline__ short8 cvt8(const float* p) {
    const float4 f0 = *(const float4*)p;
    const float4 f1 = *(const float4*)(p + 4);
    union { short8 s; __hip_bfloat162 h[4]; } u;
    u.h[0] = __float22bfloat162_rn(make_float2(f0.x, f0.y));
    u.h[1] = __float22bfloat162_rn(make_float2(f0.z, f0.w));
    u.h[2] = __float22bfloat162_rn(make_float2(f1.x, f1.y));
    u.h[3] = __float22bfloat162_rn(make_float2(f1.z, f1.w));
    return u.s;
}

// fast GELU (tanh form, exp2-based): max |err| ~1e-3, under bf16 noise.
__device__ __forceinline__ float fast_gelu(float y) {
    const float t = y * y;
    const float u = __builtin_fmaf(y * 0.044715f, t, y);
    const float e = __builtin_amdgcn_exp2f(u * -2.302118131f); // -2*sqrt(2/pi)*log2(e)
    return y * __builtin_amdgcn_rcpf(1.0f + e);
}

// ------------------------------------------------------------- K0: prep -----
// Wqkvt transpose only (Wpt/W1t/W2t ride inside k_qkv's grid). 48 blocks.
__global__ __launch_bounds__(256) void k_prep(
    const float* __restrict__ Wq, const float* __restrict__ Wk,
    const float* __restrict__ Wv, __hip_bfloat16* __restrict__ Wqkvt)
{
    const int blk = blockIdx.x, tid = threadIdx.x;
    const int i0 = blk * 1024 + tid * 4;
    const int n = i0 >> 7, d0 = i0 & 127;
    const int sec = n >> 7, m = n & 127;
    const float* W = (sec == 0) ? Wq : (sec == 1) ? Wk : Wv;
    const float* src = W + (m >> 4) * 2048 + (m & 15);
    us4 v;
    #pragma unroll
    for (int j = 0; j < 4; ++j) v[j] = f2bf(src[(d0 + j) * 16]);
    *(us4*)((unsigned short*)Wqkvt + i0) = v;
}

// ------------------------------------------------------- K1: QKV (MFMA) -----
// blocks 0..511: 32 tokens each, transposed-D GEMM. blocks 512..655: other
// weight transposes (concurrent; needed only by k_tail two launches later).
__global__ __launch_bounds__(256) void k_qkv(
    const float* __restrict__ x, const __hip_bfloat16* __restrict__ Wqkvt,
    const float* __restrict__ bq, const float* __restrict__ bk,
    const float* __restrict__ bv,
    const float* __restrict__ Wp, const float* __restrict__ W1,
    const float* __restrict__ W2,
    __hip_bfloat16* __restrict__ Wpt, __hip_bfloat16* __restrict__ W1t,
    __hip_bfloat16* __restrict__ W2t,
    __hip_bfloat16* __restrict__ qo, __hip_bfloat16* __restrict__ ko,
    __hip_bfloat16* __restrict__ vo)
{
    __shared__ __align__(16) unsigned short st[32 * 392];
    const int tid = threadIdx.x;

    if (blockIdx.x >= 512) {              // fused weight-prep tail
        const int blk = blockIdx.x - 512 + 48;   // 48..191
        us4 v;
        if (blk < 64) {                   // Wpt: 16384
            const int i0 = (blk - 48) * 1024 + tid * 4;
            const int n = i0 >> 7, d0 = i0 & 127;
            #pragma unroll
            for (int j = 0; j < 4; ++j) v[j] = f2bf(Wp[(d0 + j) * 128 + n]);
            *(us4*)((unsigned short*)Wpt + i0) = v;
        } else if (blk < 128) {           // W1t: 65536
            const int i0 = (blk - 64) * 1024 + tid * 4;
            const int n = i0 >> 7, d0 = i0 & 127;
            #pragma unroll
            for (int j = 0; j < 4; ++j) v[j] = f2bf(W1[(d0 + j) * 512 + n]);
            *(us4*)((unsigned short*)W1t + i0) = v;
        } else {                          // W2t: 65536
            const int i0 = (blk - 128) * 1024 + tid * 4;
            const int n = i0 >> 9, k0 = i0 & 511;
            #pragma unroll
            for (int j = 0; j < 4; ++j) v[j] = f2bf(W2[(k0 + j) * 128 + n]);
            *(us4*)((unsigned short*)W2t + i0) = v;
        }
        return;
    }

    const int w    = tid >> 6;
    const int lane = tid & 63;
    const int sL   = lane & 15;
    const int quad = lane >> 4;
    const int tok0 = blockIdx.x * 32;

    const unsigned short* W = (const unsigned short*)Wqkvt;

    short8 bx[2][4];
    #pragma unroll
    for (int tt = 0; tt < 2; ++tt)
        #pragma unroll
        for (int ks = 0; ks < 4; ++ks)
            bx[tt][ks] = cvt8(x + (size_t)(tok0 + tt * 16 + sL) * 128 + ks * 32 + quad * 8);

    f32x4 acc[6][2];
    #pragma unroll
    for (int ci = 0; ci < 6; ++ci)
        #pragma unroll
        for (int tt = 0; tt < 2; ++tt)
            acc[ci][tt] = (f32x4){0.f, 0.f, 0.f, 0.f};

    #pragma unroll
    for (int ks = 0; ks < 4; ++ks) {
        short8 aW[6];
        #pragma unroll
        for (int ci = 0; ci < 6; ++ci) {
            const int ct = w * 6 + ci;
            aW[ci] = *(const short8*)(W + (size_t)(ct * 16 + sL) * 128 + ks * 32 + quad * 8);
        }
        #pragma unroll
        for (int ci = 0; ci < 6; ++ci)
            #pragma unroll
            for (int tt = 0; tt < 2; ++tt)
                acc[ci][tt] = __builtin_amdgcn_mfma_f32_16x16x32_bf16(aW[ci], bx[tt][ks], acc[ci][tt], 0, 0, 0);
    }

    const float qscale = 0.3606737602f;   // 0.25 * log2(e) folded into q
    #pragma unroll
    for (int ci = 0; ci < 6; ++ci) {
        const int ct = w * 6 + ci;
        const int kind = ct >> 3;          // wave-uniform
        const int ncc = (ct & 7) * 16 + quad * 4;
        const float4 bb = *(const float4*)(((kind == 0) ? bq : (kind == 1) ? bk : bv) + ncc);
        #pragma unroll
        for (int tt = 0; tt < 2; ++tt) {
            us4 v;
            #pragma unroll
            for (int r = 0; r < 4; ++r) {
                float val = acc[ci][tt][r] + ((const float*)&bb)[r];
                if (kind == 0) val *= qscale;
                v[r] = f2bf(val);
            }
            *(us4*)(st + (tt * 16 + sL) * 392 + ct * 16 + quad * 4) = v;
        }
    }
    __syncthreads();

    const int b = tok0 >> 10, tt0 = tok0 & 1023;
    {   // q,k copy-out
        const int h = tid >> 5, tok = tid & 31;
        const unsigned short* sq = st + tok * 392 + h * 16;
        const unsigned short* sk = st + tok * 392 + 128 + h * 16;
        unsigned short* dq = (unsigned short*)qo + ((size_t)(b * 8 + h) * 1024 + tt0 + tok) * 16;
        unsigned short* dk = (unsigned short*)ko + ((size_t)(b * 8 + h) * 1024 + tt0 + tok) * 16;
        *(short8*)dq       = *(const short8*)sq;
        *(short8*)(dq + 8) = *(const short8*)(sq + 8);
        *(short8*)dk       = *(const short8*)sk;
        *(short8*)(dk + 8) = *(const short8*)(sk + 8);
    }
    if (tid < 128) {  // v copy-out (transposed)
        const int h = tid >> 4, s = tid & 15;
        unsigned short tmp[32];
        #pragma unroll
        for (int tok = 0; tok < 32; ++tok)
            tmp[tok] = st[tok * 392 + 256 + h * 16 + s];
        unsigned short* dv = (unsigned short*)vo + ((size_t)(b * 8 + h) * 16 + s) * 1024 + tt0;
        #pragma unroll
        for (int j = 0; j < 4; ++j)
            *(short8*)(dv + j * 8) = *(const short8*)(tmp + j * 8);
    }
}

// ------------------------------------------------------------ K2: attention --
// MFMA flash attention, XCD-pinned. tile = wave*16 + sub: per-block chunk-sum
// nearly uniform (48..78 vs 6..258 before) for dispatch balance.
__global__ __launch_bounds__(256) void k_attn(
    const __hip_bfloat16* __restrict__ qb, const __hip_bfloat16* __restrict__ kb,
    const __hip_bfloat16* __restrict__ vtb, __hip_bfloat16* __restrict__ att)
{
    const int bh   = blockIdx.x & 127;
    const int sub  = blockIdx.x >> 7;        // 0..15
    const int wave = threadIdx.x >> 6;
    const int lane = threadIdx.x & 63;
    const int sL   = lane & 15;
    const int q    = lane >> 4;
    const int b = bh >> 3, h = bh & 7;
    const int tile = wave * 16 + sub;        // 0..63

    const char* qbase = (const char*)qb  + (size_t)bh * NT * NHS * 2;
    const char* kbase = (const char*)kb  + (size_t)bh * NT * NHS * 2;
    const char* vbase = (const char*)vtb + (size_t)bh * NHS * NT * 2;

    const short8 zz = {0,0,0,0,0,0,0,0};

    const int t0 = tile * 16;
    const int tmy = t0 + sL;

    short8 bQ = zz;
    if (q < 2) bQ = *(const short8*)(qbase + (size_t)tmy * 32 + q * 16);

    f32x4 o = {0.f, 0.f, 0.f, 0.f};
    float lp = 0.f;

    const int nch = (t0 + 47) >> 5;
    for (int c = 0; c < nch; ++c) {
        const int u0 = c * 32;
        short8 aK0 = zz, aK1 = zz;
        if (q < 2) {
            aK0 = *(const short8*)(kbase + (size_t)(u0 + sL) * 32 + q * 16);
            aK1 = *(const short8*)(kbase + (size_t)(u0 + 16 + sL) * 32 + q * 16);
        }
        const f32x4 zc = {0.f, 0.f, 0.f, 0.f};
        f32x4 sT0 = __builtin_amdgcn_mfma_f32_16x16x32_bf16(aK0, bQ, zc, 0, 0, 0);
        f32x4 sT1 = __builtin_amdgcn_mfma_f32_16x16x32_bf16(aK1, bQ, zc, 0, 0, 0);

        int pk[4];
        if (u0 + 31 <= t0) {                 // wave-uniform: fully unmasked
            #pragma unroll
            for (int r = 0; r < 4; ++r) {
                const float p0 = __builtin_amdgcn_exp2f(sT0[r]);
                const float p1 = __builtin_amdgcn_exp2f(sT1[r]);
                lp += p0 + p1;
                __hip_bfloat162 hh = __float22bfloat162_rn(make_float2(p0, p1));
                pk[r] = *(int*)&hh;
            }
        } else {
            #pragma unroll
            for (int r = 0; r < 4; ++r) {
                const int ua = u0 + 4 * q + r;
                const float e0 = __builtin_amdgcn_exp2f(sT0[r]);
                const float e1 = __builtin_amdgcn_exp2f(sT1[r]);
                const float p0 = (ua      <= tmy) ? e0 : 0.f;
                const float p1 = (ua + 16 <= tmy) ? e1 : 0.f;
                lp += p0 + p1;
                __hip_bfloat162 hh = __float22bfloat162_rn(make_float2(p0, p1));
                pk[r] = *(int*)&hh;
            }
        }

        short8 bP;
        #pragma unroll
        for (int j = 0; j < 8; ++j) {
            const int srcq = ((q & 1) << 1) + (j >> 2);
            const int src  = (srcq << 4) + sL;
            const int g = __shfl(pk[j & 3], src);
            bP[j] = (short)((q < 2) ? (g & 0xffff) : ((unsigned)g >> 16));
        }

        const short8 aV = *(const short8*)(vbase + ((size_t)sL * NT + u0 + q * 8) * 2);
        o = __builtin_amdgcn_mfma_f32_16x16x32_bf16(aV, bP, o, 0, 0, 0);
    }

    float l = lp;
    l += __shfl_xor(l, 16);
    l += __shfl_xor(l, 32);
    const float inv = 1.0f / l;
    us4 res;
    res[0] = f2bf(o[0] * inv); res[1] = f2bf(o[1] * inv);
    res[2] = f2bf(o[2] * inv); res[3] = f2bf(o[3] * inv);
    *(us4*)((unsigned short*)att + ((size_t)b * NT + tmy) * ND + h * NHS + q * 4) = res;
}

// ------------- K3: FUSED tail: proj + LN1 + mlp1 + GELU + mlp2 + LN2 --------
// 1024 blocks x 16 tokens (was 512x32): LDS ~29.7 KB -> 5 blocks/CU (was 2),
// 2.5x occupancy to hide the serial-phase latencies.
__global__ __launch_bounds__(256) void k_tail(
    const __hip_bfloat16* __restrict__ attb, const __hip_bfloat16* __restrict__ Wpt,
    const __hip_bfloat16* __restrict__ W1t, const __hip_bfloat16* __restrict__ W2t,
    const float* __restrict__ x, const float* __restrict__ bp,
    const float* __restrict__ g1, const float* __restrict__ be1,
    const float* __restrict__ b1, const float* __restrict__ b2,
    const float* __restrict__ g2, const float* __restrict__ be2,
    float* __restrict__ out)
{
    __shared__ float ys[16][132];                            // proj-out -> ln1f
    __shared__ __align__(16) unsigned short l1b[16 * 136];   // ln1 bf16
    __shared__ __align__(16) unsigned short midb[16 * 528];  // gelu out bf16
    const int w    = threadIdx.x >> 6;
    const int lane = threadIdx.x & 63;
    const int sL   = lane & 15;
    const int quad = lane >> 4;
    const int tok0 = blockIdx.x * 16;

    // ---- phase A: out-proj GEMM (transposed-D) ----
    {
        const unsigned short* A = (const unsigned short*)attb;
        const unsigned short* W = (const unsigned short*)Wpt;
        short8 bfr[4];
        #pragma unroll
        for (int ks = 0; ks < 4; ++ks)
            bfr[ks] = *(const short8*)(A + (size_t)(tok0 + sL) * 128 + ks * 32 + quad * 8);

        f32x4 acc[2];
        acc[0] = (f32x4){0.f, 0.f, 0.f, 0.f};
        acc[1] = (f32x4){0.f, 0.f, 0.f, 0.f};

        #pragma unroll
        for (int ks = 0; ks < 4; ++ks) {
            #pragma unroll
            for (int ci = 0; ci < 2; ++ci) {
                const short8 aW = *(const short8*)(W + (size_t)((w * 2 + ci) * 16 + sL) * 128 + ks * 32 + quad * 8);
                acc[ci] = __builtin_amdgcn_mfma_f32_16x16x32_bf16(aW, bfr[ks], acc[ci], 0, 0, 0);
            }
        }
        #pragma unroll
        for (int ci = 0; ci < 2; ++ci) {
            const int n0 = (w * 2 + ci) * 16 + quad * 4;
            const float4 bb = *(const float4*)(bp + n0);
            float4 v;
            v.x = acc[ci][0] + bb.x; v.y = acc[ci][1] + bb.y;
            v.z = acc[ci][2] + bb.z; v.w = acc[ci][3] + bb.w;
            *(float4*)(&ys[sL][n0]) = v;
        }
    }
    __syncthreads();

    // ---- phase B: +x residual, LN1 -> ys (f32) and l1b (bf16) ----
    const int tok = threadIdx.x >> 4;     // 0..15
    const int l16 = threadIdx.x & 15;
    const int c0  = l16 * 8;
    {
        float vals[8];
        float s = 0.f, s2 = 0.f;
        #pragma unroll
        for (int ch = 0; ch < 2; ++ch) {
            const float4 ly = *(const float4*)&ys[tok][c0 + ch * 4];
            const float4 gx = *(const float4*)(x + (size_t)(tok0 + tok) * 128 + c0 + ch * 4);
            vals[ch*4+0] = ly.x + gx.x; vals[ch*4+1] = ly.y + gx.y;
            vals[ch*4+2] = ly.z + gx.z; vals[ch*4+3] = ly.w + gx.w;
            #pragma unroll
            for (int j = 0; j < 4; ++j) { s += vals[ch*4+j]; s2 += vals[ch*4+j] * vals[ch*4+j]; }
        }
        #pragma unroll
        for (int off = 1; off <= 8; off <<= 1) {
            s  += __shfl_xor(s, off, 16);
            s2 += __shfl_xor(s2, off, 16);
        }
        const float mean = s * (1.0f / 128.0f);
        const float var  = s2 * (1.0f / 128.0f) - mean * mean;
        const float rstd = rsqrtf(var + 1e-5f);
        #pragma unroll
        for (int ch = 0; ch < 2; ++ch) {
            const float4 gg = *(const float4*)(g1 + c0 + ch * 4);
            const float4 bb = *(const float4*)(be1 + c0 + ch * 4);
            float ln0 = (vals[ch*4+0] - mean) * rstd * gg.x + bb.x;
            float ln1v = (vals[ch*4+1] - mean) * rstd * gg.y + bb.y;
            float ln2v = (vals[ch*4+2] - mean) * rstd * gg.z + bb.z;
            float ln3 = (vals[ch*4+3] - mean) * rstd * gg.w + bb.w;
            ys[tok][c0 + ch*4 + 0] = ln0;
            ys[tok][c0 + ch*4 + 1] = ln1v;
            ys[tok][c0 + ch*4 + 2] = ln2v;
            ys[tok][c0 + ch*4 + 3] = ln3;
            us4 lb;
            lb[0] = f2bf(ln0); lb[1] = f2bf(ln1v); lb[2] = f2bf(ln2v); lb[3] = f2bf(ln3);
            *(us4*)(l1b + tok * 136 + c0 + ch * 4) = lb;
        }
    }
    __syncthreads();

    // ---- phase C: mlp1 GEMM (transposed-D) + fast GELU -> midb (LDS) ----
    {
        const unsigned short* W = (const unsigned short*)W1t;
        short8 bl[4];
        #pragma unroll
        for (int ks = 0; ks < 4; ++ks)
            bl[ks] = *(const short8*)(l1b + sL * 136 + ks * 32 + quad * 8);

        f32x4 acc[8];
        #pragma unroll
        for (int ci = 0; ci < 8; ++ci)
            acc[ci] = (f32x4){0.f, 0.f, 0.f, 0.f};

        #pragma unroll
        for (int ks = 0; ks < 4; ++ks) {
            #pragma unroll
            for (int ci = 0; ci < 8; ++ci) {
                const short8 aW = *(const short8*)(W + (size_t)((w * 8 + ci) * 16 + sL) * 128 + ks * 32 + quad * 8);
                acc[ci] = __builtin_amdgcn_mfma_f32_16x16x32_bf16(aW, bl[ks], acc[ci], 0, 0, 0);
            }
        }
        #pragma unroll
        for (int ci = 0; ci < 8; ++ci) {
            const int n0 = (w * 8 + ci) * 16 + quad * 4;
            const float4 bb = *(const float4*)(b1 + n0);
            us4 v;
            v[0] = f2bf(fast_gelu(acc[ci][0] + bb.x));
            v[1] = f2bf(fast_gelu(acc[ci][1] + bb.y));
            v[2] = f2bf(fast_gelu(acc[ci][2] + bb.z));
            v[3] = f2bf(fast_gelu(acc[ci][3] + bb.w));
            *(us4*)(midb + sL * 528 + n0) = v;
        }
    }
    __syncthreads();

    // ---- phase D: mlp2 GEMM (transposed-D) ----
    f32x4 acc2[2];
    acc2[0] = (f32x4){0.f, 0.f, 0.f, 0.f};
    acc2[1] = (f32x4){0.f, 0.f, 0.f, 0.f};
    {
        const unsigned short* W = (const unsigned short*)W2t;
        #pragma unroll
        for (int ks = 0; ks < 16; ++ks) {
            const short8 bm = *(const short8*)(midb + (size_t)sL * 528 + ks * 32 + quad * 8);
            const short8 aW0 = *(const short8*)(W + (size_t)((w * 2) * 16 + sL) * 512 + ks * 32 + quad * 8);
            const short8 aW1 = *(const short8*)(W + (size_t)((w * 2 + 1) * 16 + sL) * 512 + ks * 32 + quad * 8);
            acc2[0] = __builtin_amdgcn_mfma_f32_16x16x32_bf16(aW0, bm, acc2[0], 0, 0, 0);
            acc2[1] = __builtin_amdgcn_mfma_f32_16x16x32_bf16(aW1, bm, acc2[1], 0, 0, 0);
        }
    }
    __syncthreads();                         // all midb reads done
    float* ys2 = (float*)midb;               // alias: 16 x 132 f32
    #pragma unroll
    for (int ci = 0; ci < 2; ++ci) {
        const int n0 = (w * 2 + ci) * 16 + quad * 4;
        const float4 bb = *(const float4*)(b2 + n0);
        float4 v;
        v.x = acc2[ci][0] + bb.x; v.y = acc2[ci][1] + bb.y;
        v.z = acc2[ci][2] + bb.z; v.w = acc2[ci][3] + bb.w;
        *(float4*)(ys2 + sL * 132 + n0) = v;
    }
    __syncthreads();

    // ---- phase E: +ln1 residual, LN2 -> out ----
    {
        float vals[8];
        float s = 0.f, s2 = 0.f;
        #pragma unroll
        for (int ch = 0; ch < 2; ++ch) {
            const float4 ly = *(const float4*)(ys2 + tok * 132 + c0 + ch * 4);
            const float4 gx = *(const float4*)&ys[tok][c0 + ch * 4];
            vals[ch*4+0] = ly.x + gx.x; vals[ch*4+1] = ly.y + gx.y;
            vals[ch*4+2] = ly.z + gx.z; vals[ch*4+3] = ly.w + gx.w;
            #pragma unroll
            for (int j = 0; j < 4; ++j) { s += vals[ch*4+j]; s2 += vals[ch*4+j] * vals[ch*4+j]; }
        }
        #pragma unroll
        for (int off = 1; off <= 8; off <<= 1) {
            s  += __shfl_xor(s, off, 16);
            s2 += __shfl_xor(s2, off, 16);
        }
        const float mean = s * (1.0f / 128.0f);
        const float var  = s2 * (1.0f / 128.0f) - mean * mean;
        const float rstd = rsqrtf(var + 1e-5f);
        #pragma unroll
        for (int ch = 0; ch < 2; ++ch) {
            const float4 gg = *(const float4*)(g2 + c0 + ch * 4);
            const float4 bb = *(const float4*)(be2 + c0 + ch * 4);
            float4 ln;
            ln.x = (vals[ch*4+0] - mean) * rstd * gg.x + bb.x;
            ln.y = (vals[ch*4+1] - mean) * rstd * gg.y + bb.y;
            ln.z = (vals[ch*4+2] - mean) * rstd * gg.z + bb.z;
            ln.w = (vals[ch*4+3] - mean) * rstd * gg.w + bb.w;
            *(float4*)(out + (size_t)(tok0 + tok) * 128 + c0 + ch * 4) = ln;
        }
    }
}

// ----------------------------------------------------------------- launcher --
extern "C" void kernel_launch(void* const* d_in, const int* in_sizes, int n_in,
                              void* d_out, int out_size, void* d_ws, size_t ws_size,
                              hipStream_t stream)
{
    (void)in_sizes; (void)n_in; (void)out_size; (void)ws_size;
    const float* x   = (const float*)d_in[0];
    const float* Wq  = (const float*)d_in[1];
    const float* bq  = (const float*)d_in[2];
    const float* Wk  = (const float*)d_in[3];
    const float* bk  = (const float*)d_in[4];
    const float* Wv  = (const float*)d_in[5];
    const float* bv  = (const float*)d_in[6];
    const float* Wp  = (const float*)d_in[7];
    const float* bp  = (const float*)d_in[8];
    const float* W1  = (const float*)d_in[9];
    const float* b1  = (const float*)d_in[10];
    const float* W2  = (const float*)d_in[11];
    const float* b2  = (const float*)d_in[12];
    const float* g1  = (const float*)d_in[13];
    const float* be1 = (const float*)d_in[14];
    const float* g2  = (const float*)d_in[15];
    const float* be2 = (const float*)d_in[16];
    float* out = (float*)d_out;

    char* wsb = (char*)d_ws;
    // ws map: qb 0-4M | kb 4-8M | vtb 8-12M | attb 12-16M | weights @16M
    __hip_bfloat16* qb   = (__hip_bfloat16*)wsb;
    __hip_bfloat16* kb   = (__hip_bfloat16*)(wsb + (4u  << 20));
    __hip_bfloat16* vtb  = (__hip_bfloat16*)(wsb + (8u  << 20));
    __hip_bfloat16* attb = (__hip_bfloat16*)(wsb + (12u << 20));
    __hip_bfloat16* Wqkvt= (__hip_bfloat16*)(wsb + (16u << 20));
    __hip_bfloat16* Wpt  = (__hip_bfloat16*)(wsb + (16u << 20) + (96u  << 10));
    __hip_bfloat16* W1t  = (__hip_bfloat16*)(wsb + (16u << 20) + (128u << 10));
    __hip_bfloat16* W2t  = (__hip_bfloat16*)(wsb + (16u << 20) + (256u << 10));

    k_prep<<<48,   256, 0, stream>>>(Wq, Wk, Wv, Wqkvt);
    k_qkv <<<656,  256, 0, stream>>>(x, Wqkvt, bq, bk, bv, Wp, W1, W2,
                                     Wpt, W1t, W2t, qb, kb, vtb);
    k_attn<<<2048, 256, 0, stream>>>(qb, kb, vtb, attb);
    k_tail<<<1024, 256, 0, stream>>>(attb, Wpt, W1t, W2t, x, bp, g1, be1,
                                     b1, b2, g2, be2, out);
}

// Round 13
// 164.182 us; speedup vs baseline: 1.0701x; 1.0701x over previous
//
#include <hip/hip_runtime.h>
#include <hip/hip_bf16.h>
#include <math.h>

constexpr int NB  = 16;
constexpr int NT  = 1024;
constexpr int ND  = 128;
constexpr int NH  = 8;
constexpr int NHS = 16;
constexpr int NDH = 512;
constexpr long NBT = (long)NB * NT;   // 16384 tokens

typedef __attribute__((ext_vector_type(8))) short short8;
typedef __attribute__((ext_vector_type(4))) float f32x4;
typedef __attribute__((ext_vector_type(4))) unsigned short us4;

__device__ __forceinline__ unsigned short f2bf(float f) {
    __hip_bfloat16 h = __float2bfloat16(f);
    return *(unsigned short*)&h;
}
__device__ __forceinline__ float b2f(unsigned short u) {
    union { unsigned int i; float f; } t;
    t.i = ((unsigned int)u) << 16;
    return t.f;
}

// f32[8] -> bf16x8 fragment (RNE packed converts)
__device__ __forceinline__ short8 cvt8(const float* p) {
    const float4 f0 = *(const float4*)p;
    const float4 f1 = *(const float4*)(p + 4);
    union { short8 s; __hip_bfloat162 h[4]; } u;
    u.h[0] = __float22bfloat162_rn(make_float2(f0.x, f0.y));
    u.h[1] = __float22bfloat162_rn(make_float2(f0.z, f0.w));
    u.h[2] = __float22bfloat162_rn(make_float2(f1.x, f1.y));
    u.h[3] = __float22bfloat162_rn(make_float2(f1.z, f1.w));
    return u.s;
}

// fast GELU (tanh form, exp2-based): max |err| ~1e-3, under bf16 noise.
__device__ __forceinline__ float fast_gelu(float y) {
    const float t = y * y;
    const float u = __builtin_fmaf(y * 0.044715f, t, y);
    const float e = __builtin_amdgcn_exp2f(u * -2.302118131f); // -2*sqrt(2/pi)*log2(e)
    return y * __builtin_amdgcn_rcpf(1.0f + e);
}

// ------------------------------------------------------------- K0: prep -----
// Wqkvt transpose only (Wpt/W1t/W2t ride inside k_qkv's grid). 48 blocks.
__global__ __launch_bounds__(256) void k_prep(
    const float* __restrict__ Wq, const float* __restrict__ Wk,
    const float* __restrict__ Wv, __hip_bfloat16* __restrict__ Wqkvt)
{
    const int blk = blockIdx.x, tid = threadIdx.x;
    const int i0 = blk * 1024 + tid * 4;
    const int n = i0 >> 7, d0 = i0 & 127;
    const int sec = n >> 7, m = n & 127;
    const float* W = (sec == 0) ? Wq : (sec == 1) ? Wk : Wv;
    const float* src = W + (m >> 4) * 2048 + (m & 15);
    us4 v;
    #pragma unroll
    for (int j = 0; j < 4; ++j) v[j] = f2bf(src[(d0 + j) * 16]);
    *(us4*)((unsigned short*)Wqkvt + i0) = v;
}

// ------------------------------------------------------- K1: QKV (MFMA) -----
// blocks 0..511: 32 tokens each, transposed-D GEMM. blocks 512..655: other
// weight transposes (concurrent; needed only by k_tail two launches later).
__global__ __launch_bounds__(256) void k_qkv(
    const float* __restrict__ x, const __hip_bfloat16* __restrict__ Wqkvt,
    const float* __restrict__ bq, const float* __restrict__ bk,
    const float* __restrict__ bv,
    const float* __restrict__ Wp, const float* __restrict__ W1,
    const float* __restrict__ W2,
    __hip_bfloat16* __restrict__ Wpt, __hip_bfloat16* __restrict__ W1t,
    __hip_bfloat16* __restrict__ W2t,
    __hip_bfloat16* __restrict__ qo, __hip_bfloat16* __restrict__ ko,
    __hip_bfloat16* __restrict__ vo)
{
    __shared__ __align__(16) unsigned short st[32 * 392];
    const int tid = threadIdx.x;

    if (blockIdx.x >= 512) {              // fused weight-prep tail
        const int blk = blockIdx.x - 512 + 48;   // 48..191
        us4 v;
        if (blk < 64) {                   // Wpt: 16384
            const int i0 = (blk - 48) * 1024 + tid * 4;
            const int n = i0 >> 7, d0 = i0 & 127;
            #pragma unroll
            for (int j = 0; j < 4; ++j) v[j] = f2bf(Wp[(d0 + j) * 128 + n]);
            *(us4*)((unsigned short*)Wpt + i0) = v;
        } else if (blk < 128) {           // W1t: 65536
            const int i0 = (blk - 64) * 1024 + tid * 4;
            const int n = i0 >> 7, d0 = i0 & 127;
            #pragma unroll
            for (int j = 0; j < 4; ++j) v[j] = f2bf(W1[(d0 + j) * 512 + n]);
            *(us4*)((unsigned short*)W1t + i0) = v;
        } else {                          // W2t: 65536
            const int i0 = (blk - 128) * 1024 + tid * 4;
            const int n = i0 >> 9, k0 = i0 & 511;
            #pragma unroll
            for (int j = 0; j < 4; ++j) v[j] = f2bf(W2[(k0 + j) * 128 + n]);
            *(us4*)((unsigned short*)W2t + i0) = v;
        }
        return;
    }

    const int w    = tid >> 6;
    const int lane = tid & 63;
    const int sL   = lane & 15;
    const int quad = lane >> 4;
    const int tok0 = blockIdx.x * 32;

    const unsigned short* W = (const unsigned short*)Wqkvt;

    short8 bx[2][4];
    #pragma unroll
    for (int tt = 0; tt < 2; ++tt)
        #pragma unroll
        for (int ks = 0; ks < 4; ++ks)
            bx[tt][ks] = cvt8(x + (size_t)(tok0 + tt * 16 + sL) * 128 + ks * 32 + quad * 8);

    f32x4 acc[6][2];
    #pragma unroll
    for (int ci = 0; ci < 6; ++ci)
        #pragma unroll
        for (int tt = 0; tt < 2; ++tt)
            acc[ci][tt] = (f32x4){0.f, 0.f, 0.f, 0.f};

    #pragma unroll
    for (int ks = 0; ks < 4; ++ks) {
        short8 aW[6];
        #pragma unroll
        for (int ci = 0; ci < 6; ++ci) {
            const int ct = w * 6 + ci;
            aW[ci] = *(const short8*)(W + (size_t)(ct * 16 + sL) * 128 + ks * 32 + quad * 8);
        }
        #pragma unroll
        for (int ci = 0; ci < 6; ++ci)
            #pragma unroll
            for (int tt = 0; tt < 2; ++tt)
                acc[ci][tt] = __builtin_amdgcn_mfma_f32_16x16x32_bf16(aW[ci], bx[tt][ks], acc[ci][tt], 0, 0, 0);
    }

    const float qscale = 0.3606737602f;   // 0.25 * log2(e) folded into q
    #pragma unroll
    for (int ci = 0; ci < 6; ++ci) {
        const int ct = w * 6 + ci;
        const int kind = ct >> 3;          // wave-uniform
        const int ncc = (ct & 7) * 16 + quad * 4;
        const float4 bb = *(const float4*)(((kind == 0) ? bq : (kind == 1) ? bk : bv) + ncc);
        #pragma unroll
        for (int tt = 0; tt < 2; ++tt) {
            us4 v;
            #pragma unroll
            for (int r = 0; r < 4; ++r) {
                float val = acc[ci][tt][r] + ((const float*)&bb)[r];
                if (kind == 0) val *= qscale;
                v[r] = f2bf(val);
            }
            *(us4*)(st + (tt * 16 + sL) * 392 + ct * 16 + quad * 4) = v;
        }
    }
    __syncthreads();

    const int b = tok0 >> 10, tt0 = tok0 & 1023;
    {   // q,k copy-out
        const int h = tid >> 5, tok = tid & 31;
        const unsigned short* sq = st + tok * 392 + h * 16;
        const unsigned short* sk = st + tok * 392 + 128 + h * 16;
        unsigned short* dq = (unsigned short*)qo + ((size_t)(b * 8 + h) * 1024 + tt0 + tok) * 16;
        unsigned short* dk = (unsigned short*)ko + ((size_t)(b * 8 + h) * 1024 + tt0 + tok) * 16;
        *(short8*)dq       = *(const short8*)sq;
        *(short8*)(dq + 8) = *(const short8*)(sq + 8);
        *(short8*)dk       = *(const short8*)sk;
        *(short8*)(dk + 8) = *(const short8*)(sk + 8);
    }
    if (tid < 128) {  // v copy-out (transposed)
        const int h = tid >> 4, s = tid & 15;
        unsigned short tmp[32];
        #pragma unroll
        for (int tok = 0; tok < 32; ++tok)
            tmp[tok] = st[tok * 392 + 256 + h * 16 + s];
        unsigned short* dv = (unsigned short*)vo + ((size_t)(b * 8 + h) * 16 + s) * 1024 + tt0;
        #pragma unroll
        for (int j = 0; j < 4; ++j)
            *(short8*)(dv + j * 8) = *(const short8*)(tmp + j * 8);
    }
}

// ------------------------------------------------------------ K2: attention --
// MFMA flash attention, XCD-pinned (bh = blockIdx&127), one 16-row tile per
// wave (tile = sub*4 + wave). R10-verified.
__global__ __launch_bounds__(256) void k_attn(
    const __hip_bfloat16* __restrict__ qb, const __hip_bfloat16* __restrict__ kb,
    const __hip_bfloat16* __restrict__ vtb, __hip_bfloat16* __restrict__ att)
{
    const int bh   = blockIdx.x & 127;
    const int sub  = blockIdx.x >> 7;        // 0..15
    const int wave = threadIdx.x >> 6;
    const int lane = threadIdx.x & 63;
    const int sL   = lane & 15;
    const int q    = lane >> 4;
    const int b = bh >> 3, h = bh & 7;
    const int tile = sub * 4 + wave;         // 0..63

    const char* qbase = (const char*)qb  + (size_t)bh * NT * NHS * 2;
    const char* kbase = (const char*)kb  + (size_t)bh * NT * NHS * 2;
    const char* vbase = (const char*)vtb + (size_t)bh * NHS * NT * 2;

    const short8 zz = {0,0,0,0,0,0,0,0};

    const int t0 = tile * 16;
    const int tmy = t0 + sL;

    short8 bQ = zz;
    if (q < 2) bQ = *(const short8*)(qbase + (size_t)tmy * 32 + q * 16);

    f32x4 o = {0.f, 0.f, 0.f, 0.f};
    float lp = 0.f;

    const int nch = (t0 + 47) >> 5;
    for (int c = 0; c < nch; ++c) {
        const int u0 = c * 32;
        short8 aK0 = zz, aK1 = zz;
        if (q < 2) {
            aK0 = *(const short8*)(kbase + (size_t)(u0 + sL) * 32 + q * 16);
            aK1 = *(const short8*)(kbase + (size_t)(u0 + 16 + sL) * 32 + q * 16);
        }
        const f32x4 zc = {0.f, 0.f, 0.f, 0.f};
        f32x4 sT0 = __builtin_amdgcn_mfma_f32_16x16x32_bf16(aK0, bQ, zc, 0, 0, 0);
        f32x4 sT1 = __builtin_amdgcn_mfma_f32_16x16x32_bf16(aK1, bQ, zc, 0, 0, 0);

        int pk[4];
        if (u0 + 31 <= t0) {                 // wave-uniform: fully unmasked
            #pragma unroll
            for (int r = 0; r < 4; ++r) {
                const float p0 = __builtin_amdgcn_exp2f(sT0[r]);
                const float p1 = __builtin_amdgcn_exp2f(sT1[r]);
                lp += p0 + p1;
                __hip_bfloat162 hh = __float22bfloat162_rn(make_float2(p0, p1));
                pk[r] = *(int*)&hh;
            }
        } else {
            #pragma unroll
            for (int r = 0; r < 4; ++r) {
                const int ua = u0 + 4 * q + r;
                const float e0 = __builtin_amdgcn_exp2f(sT0[r]);
                const float e1 = __builtin_amdgcn_exp2f(sT1[r]);
                const float p0 = (ua      <= tmy) ? e0 : 0.f;
                const float p1 = (ua + 16 <= tmy) ? e1 : 0.f;
                lp += p0 + p1;
                __hip_bfloat162 hh = __float22bfloat162_rn(make_float2(p0, p1));
                pk[r] = *(int*)&hh;
            }
        }

        short8 bP;
        #pragma unroll
        for (int j = 0; j < 8; ++j) {
            const int srcq = ((q & 1) << 1) + (j >> 2);
            const int src  = (srcq << 4) + sL;
            const int g = __shfl(pk[j & 3], src);
            bP[j] = (short)((q < 2) ? (g & 0xffff) : ((unsigned)g >> 16));
        }

        const short8 aV = *(const short8*)(vbase + ((size_t)sL * NT + u0 + q * 8) * 2);
        o = __builtin_amdgcn_mfma_f32_16x16x32_bf16(aV, bP, o, 0, 0, 0);
    }

    float l = lp;
    l += __shfl_xor(l, 16);
    l += __shfl_xor(l, 32);
    const float inv = 1.0f / l;
    us4 res;
    res[0] = f2bf(o[0] * inv); res[1] = f2bf(o[1] * inv);
    res[2] = f2bf(o[2] * inv); res[3] = f2bf(o[3] * inv);
    *(us4*)((unsigned short*)att + ((size_t)b * NT + tmy) * ND + h * NHS + q * 4) = res;
}

// ------------- K3: FUSED tail: proj + LN1 + mlp1 + GELU + mlp2 + LN2 --------
// R10-exact 256-thread partitioning, with union LDS: buf (33 KB) serves as
// f32 proj-out (A->B, pitch 132), bf16 GELU mid (C->D, pitch 528), f32
// mlp2-out (D->E, pitch 132) — lifetimes separated by existing barriers.
// Phase-E residual reads bf16 l1b (adds <0.01 abs err, budget 0.098).
// LDS 59.4 -> 42.5 KB: 3 blocks/CU (was 2), 12 waves/CU for the
// latency-bound phases (R11 PMC: MfmaUtil 3.8%, VALUBusy 9%).
__global__ __launch_bounds__(256) void k_tail(
    const __hip_bfloat16* __restrict__ attb, const __hip_bfloat16* __restrict__ Wpt,
    const __hip_bfloat16* __restrict__ W1t, const __hip_bfloat16* __restrict__ W2t,
    const float* __restrict__ x, const float* __restrict__ bp,
    const float* __restrict__ g1, const float* __restrict__ be1,
    const float* __restrict__ b1, const float* __restrict__ b2,
    const float* __restrict__ g2, const float* __restrict__ be2,
    float* __restrict__ out)
{
    __shared__ __align__(16) unsigned short buf[32 * 528];   // 33 KB union
    __shared__ __align__(16) unsigned short l1b[32 * 136];   // ln1 bf16, B->E
    float* ysA           = (float*)buf;       // pitch 132 (phases A->B)
    unsigned short* midb = buf;               // pitch 528 (phases C->D)
    float* ys2           = (float*)buf;       // pitch 132 (phases D->E)
    const int w    = threadIdx.x >> 6;
    const int lane = threadIdx.x & 63;
    const int sL   = lane & 15;
    const int quad = lane >> 4;
    const int tok0 = blockIdx.x * 32;

    // ---- phase A: out-proj GEMM (transposed-D) ----
    {
        const unsigned short* A = (const unsigned short*)attb;
        const unsigned short* W = (const unsigned short*)Wpt;
        short8 bfr[2][4];
        #pragma unroll
        for (int tt = 0; tt < 2; ++tt)
            #pragma unroll
            for (int ks = 0; ks < 4; ++ks)
                bfr[tt][ks] = *(const short8*)(A + (size_t)(tok0 + tt * 16 + sL) * 128 + ks * 32 + quad * 8);

        f32x4 acc[2][2];                   // [ci = n-tile][tt]
        #pragma unroll
        for (int ci = 0; ci < 2; ++ci)
            #pragma unroll
            for (int tt = 0; tt < 2; ++tt)
                acc[ci][tt] = (f32x4){0.f, 0.f, 0.f, 0.f};

        #pragma unroll
        for (int ks = 0; ks < 4; ++ks) {
            short8 aW[2];
            #pragma unroll
            for (int ci = 0; ci < 2; ++ci)
                aW[ci] = *(const short8*)(W + (size_t)((w * 2 + ci) * 16 + sL) * 128 + ks * 32 + quad * 8);
            #pragma unroll
            for (int ci = 0; ci < 2; ++ci)
                #pragma unroll
                for (int tt = 0; tt < 2; ++tt)
                    acc[ci][tt] = __builtin_amdgcn_mfma_f32_16x16x32_bf16(aW[ci], bfr[tt][ks], acc[ci][tt], 0, 0, 0);
        }
        #pragma unroll
        for (int ci = 0; ci < 2; ++ci) {
            const int n0 = (w * 2 + ci) * 16 + quad * 4;
            const float4 bb = *(const float4*)(bp + n0);
            #pragma unroll
            for (int tt = 0; tt < 2; ++tt) {
                float4 v;
                v.x = acc[ci][tt][0] + bb.x; v.y = acc[ci][tt][1] + bb.y;
                v.z = acc[ci][tt][2] + bb.z; v.w = acc[ci][tt][3] + bb.w;
                *(float4*)(ysA + (size_t)(tt * 16 + sL) * 132 + n0) = v;
            }
        }
    }
    __syncthreads();

    // ---- phase B: +x residual, LN1 -> l1b (bf16 only; ysA becomes dead) ----
    const int tok = threadIdx.x >> 3;
    const int l8  = threadIdx.x & 7;
    const int c0  = l8 * 16;
    {
        float vals[16];
        float s = 0.f, s2 = 0.f;
        #pragma unroll
        for (int ch = 0; ch < 4; ++ch) {
            const float4 ly = *(const float4*)(ysA + (size_t)tok * 132 + c0 + ch * 4);
            const float4 gx = *(const float4*)(x + (size_t)(tok0 + tok) * 128 + c0 + ch * 4);
            vals[ch*4+0] = ly.x + gx.x; vals[ch*4+1] = ly.y + gx.y;
            vals[ch*4+2] = ly.z + gx.z; vals[ch*4+3] = ly.w + gx.w;
            #pragma unroll
            for (int j = 0; j < 4; ++j) { s += vals[ch*4+j]; s2 += vals[ch*4+j] * vals[ch*4+j]; }
        }
        #pragma unroll
        for (int off = 1; off <= 4; off <<= 1) {
            s  += __shfl_xor(s, off, 8);
            s2 += __shfl_xor(s2, off, 8);
        }
        const float mean = s * (1.0f / 128.0f);
        const float var  = s2 * (1.0f / 128.0f) - mean * mean;
        const float rstd = rsqrtf(var + 1e-5f);
        #pragma unroll
        for (int ch = 0; ch < 4; ++ch) {
            const float4 gg = *(const float4*)(g1 + c0 + ch * 4);
            const float4 bb = *(const float4*)(be1 + c0 + ch * 4);
            const float ln0  = (vals[ch*4+0] - mean) * rstd * gg.x + bb.x;
            const float ln1v = (vals[ch*4+1] - mean) * rstd * gg.y + bb.y;
            const float ln2v = (vals[ch*4+2] - mean) * rstd * gg.z + bb.z;
            const float ln3  = (vals[ch*4+3] - mean) * rstd * gg.w + bb.w;
            us4 lb;
            lb[0] = f2bf(ln0); lb[1] = f2bf(ln1v); lb[2] = f2bf(ln2v); lb[3] = f2bf(ln3);
            *(us4*)(l1b + tok * 136 + c0 + ch * 4) = lb;
        }
    }
    __syncthreads();

    // ---- phase C: mlp1 GEMM (transposed-D) + fast GELU -> midb (buf) ----
    {
        const unsigned short* W = (const unsigned short*)W1t;
        short8 bl[2][4];
        #pragma unroll
        for (int tt = 0; tt < 2; ++tt)
            #pragma unroll
            for (int ks = 0; ks < 4; ++ks)
                bl[tt][ks] = *(const short8*)(l1b + (tt * 16 + sL) * 136 + ks * 32 + quad * 8);

        f32x4 acc[8][2];
        #pragma unroll
        for (int ci = 0; ci < 8; ++ci)
            #pragma unroll
            for (int tt = 0; tt < 2; ++tt)
                acc[ci][tt] = (f32x4){0.f, 0.f, 0.f, 0.f};

        #pragma unroll
        for (int ks = 0; ks < 4; ++ks) {
            short8 aW[8];
            #pragma unroll
            for (int ci = 0; ci < 8; ++ci)
                aW[ci] = *(const short8*)(W + (size_t)((w * 8 + ci) * 16 + sL) * 128 + ks * 32 + quad * 8);
            #pragma unroll
            for (int ci = 0; ci < 8; ++ci)
                #pragma unroll
                for (int tt = 0; tt < 2; ++tt)
                    acc[ci][tt] = __builtin_amdgcn_mfma_f32_16x16x32_bf16(aW[ci], bl[tt][ks], acc[ci][tt], 0, 0, 0);
        }
        #pragma unroll
        for (int ci = 0; ci < 8; ++ci) {
            const int n0 = (w * 8 + ci) * 16 + quad * 4;
            const float4 bb = *(const float4*)(b1 + n0);
            #pragma unroll
            for (int tt = 0; tt < 2; ++tt) {
                us4 v;
                v[0] = f2bf(fast_gelu(acc[ci][tt][0] + bb.x));
                v[1] = f2bf(fast_gelu(acc[ci][tt][1] + bb.y));
                v[2] = f2bf(fast_gelu(acc[ci][tt][2] + bb.z));
                v[3] = f2bf(fast_gelu(acc[ci][tt][3] + bb.w));
                *(us4*)(midb + (tt * 16 + sL) * 528 + n0) = v;
            }
        }
    }
    __syncthreads();

    // ---- phase D: mlp2 GEMM (transposed-D) ----
    f32x4 acc2[2][2];
    #pragma unroll
    for (int ci = 0; ci < 2; ++ci)
        #pragma unroll
        for (int tt = 0; tt < 2; ++tt)
            acc2[ci][tt] = (f32x4){0.f, 0.f, 0.f, 0.f};
    {
        const unsigned short* W = (const unsigned short*)W2t;
        #pragma unroll
        for (int ks = 0; ks < 16; ++ks) {
            const short8 bm0 = *(const short8*)(midb + (size_t)sL * 528 + ks * 32 + quad * 8);
            const short8 bm1 = *(const short8*)(midb + (size_t)(16 + sL) * 528 + ks * 32 + quad * 8);
            const short8 aW0 = *(const short8*)(W + (size_t)((w * 2) * 16 + sL) * 512 + ks * 32 + quad * 8);
            const short8 aW1 = *(const short8*)(W + (size_t)((w * 2 + 1) * 16 + sL) * 512 + ks * 32 + quad * 8);
            acc2[0][0] = __builtin_amdgcn_mfma_f32_16x16x32_bf16(aW0, bm0, acc2[0][0], 0, 0, 0);
            acc2[0][1] = __builtin_amdgcn_mfma_f32_16x16x32_bf16(aW0, bm1, acc2[0][1], 0, 0, 0);
            acc2[1][0] = __builtin_amdgcn_mfma_f32_16x16x32_bf16(aW1, bm0, acc2[1][0], 0, 0, 0);
            acc2[1][1] = __builtin_amdgcn_mfma_f32_16x16x32_bf16(aW1, bm1, acc2[1][1], 0, 0, 0);
        }
    }
    __syncthreads();                         // all midb reads done
    #pragma unroll
    for (int ci = 0; ci < 2; ++ci) {
        const int n0 = (w * 2 + ci) * 16 + quad * 4;
        const float4 bb = *(const float4*)(b2 + n0);
        #pragma unroll
        for (int tt = 0; tt < 2; ++tt) {
            float4 v;
            v.x = acc2[ci][tt][0] + bb.x; v.y = acc2[ci][tt][1] + bb.y;
            v.z = acc2[ci][tt][2] + bb.z; v.w = acc2[ci][tt][3] + bb.w;
            *(float4*)(ys2 + (size_t)(tt * 16 + sL) * 132 + n0) = v;
        }
    }
    __syncthreads();

    // ---- phase E: +ln1 residual (bf16 from l1b), LN2 -> out ----
    {
        float vals[16];
        float s = 0.f, s2 = 0.f;
        #pragma unroll
        for (int ch = 0; ch < 4; ++ch) {
            const float4 ly = *(const float4*)(ys2 + (size_t)tok * 132 + c0 + ch * 4);
            const us4 lb = *(const us4*)(l1b + tok * 136 + c0 + ch * 4);
            vals[ch*4+0] = ly.x + b2f(lb[0]); vals[ch*4+1] = ly.y + b2f(lb[1]);
            vals[ch*4+2] = ly.z + b2f(lb[2]); vals[ch*4+3] = ly.w + b2f(lb[3]);
            #pragma unroll
            for (int j = 0; j < 4; ++j) { s += vals[ch*4+j]; s2 += vals[ch*4+j] * vals[ch*4+j]; }
        }
        #pragma unroll
        for (int off = 1; off <= 4; off <<= 1) {
            s  += __shfl_xor(s, off, 8);
            s2 += __shfl_xor(s2, off, 8);
        }
        const float mean = s * (1.0f / 128.0f);
        const float var  = s2 * (1.0f / 128.0f) - mean * mean;
        const float rstd = rsqrtf(var + 1e-5f);
        #pragma unroll
        for (int ch = 0; ch < 4; ++ch) {
            const float4 gg = *(const float4*)(g2 + c0 + ch * 4);
            const float4 bb = *(const float4*)(be2 + c0 + ch * 4);
            float4 ln;
            ln.x = (vals[ch*4+0] - mean) * rstd * gg.x + bb.x;
            ln.y = (vals[ch*4+1] - mean) * rstd * gg.y + bb.y;
            ln.z = (vals[ch*4+2] - mean) * rstd * gg.z + bb.z;
            ln.w = (vals[ch*4+3] - mean) * rstd * gg.w + bb.w;
            *(float4*)(out + (size_t)(tok0 + tok) * 128 + c0 + ch * 4) = ln;
        }
    }
}

// ----------------------------------------------------------------- launcher --
extern "C" void kernel_launch(void* const* d_in, const int* in_sizes, int n_in,
                              void* d_out, int out_size, void* d_ws, size_t ws_size,
                              hipStream_t stream)
{
    (void)in_sizes; (void)n_in; (void)out_size; (void)ws_size;
    const float* x   = (const float*)d_in[0];
    const float* Wq  = (const float*)d_in[1];
    const float* bq  = (const float*)d_in[2];
    const float* Wk  = (const float*)d_in[3];
    const float* bk  = (const float*)d_in[4];
    const float* Wv  = (const float*)d_in[5];
    const float* bv  = (const float*)d_in[6];
    const float* Wp  = (const float*)d_in[7];
    const float* bp  = (const float*)d_in[8];
    const float* W1  = (const float*)d_in[9];
    const float* b1  = (const float*)d_in[10];
    const float* W2  = (const float*)d_in[11];
    const float* b2  = (const float*)d_in[12];
    const float* g1  = (const float*)d_in[13];
    const float* be1 = (const float*)d_in[14];
    const float* g2  = (const float*)d_in[15];
    const float* be2 = (const float*)d_in[16];
    float* out = (float*)d_out;

    char* wsb = (char*)d_ws;
    // ws map: qb 0-4M | kb 4-8M | vtb 8-12M | attb 12-16M | weights @16M
    __hip_bfloat16* qb   = (__hip_bfloat16*)wsb;
    __hip_bfloat16* kb   = (__hip_bfloat16*)(wsb + (4u  << 20));
    __hip_bfloat16* vtb  = (__hip_bfloat16*)(wsb + (8u  << 20));
    __hip_bfloat16* attb = (__hip_bfloat16*)(wsb + (12u << 20));
    __hip_bfloat16* Wqkvt= (__hip_bfloat16*)(wsb + (16u << 20));
    __hip_bfloat16* Wpt  = (__hip_bfloat16*)(wsb + (16u << 20) + (96u  << 10));
    __hip_bfloat16* W1t  = (__hip_bfloat16*)(wsb + (16u << 20) + (128u << 10));
    __hip_bfloat16* W2t  = (__hip_bfloat16*)(wsb + (16u << 20) + (256u << 10));

    k_prep<<<48,   256, 0, stream>>>(Wq, Wk, Wv, Wqkvt);
    k_qkv <<<656,  256, 0, stream>>>(x, Wqkvt, bq, bk, bv, Wp, W1, W2,
                                     Wpt, W1t, W2t, qb, kb, vtb);
    k_attn<<<2048, 256, 0, stream>>>(qb, kb, vtb, attb);
    k_tail<<<512,  256, 0, stream>>>(attb, Wpt, W1t, W2t, x, bp, g1, be1,
                                     b1, b2, g2, be2, out);
}